// Round 13
// baseline (314.825 us; speedup 1.0000x reference)
//
#include <hip/hip_runtime.h>
#include <hip/hip_bf16.h>

typedef __attribute__((ext_vector_type(8))) __bf16 bf16x8;
typedef __attribute__((ext_vector_type(4))) float f32x4;
typedef __attribute__((ext_vector_type(8))) unsigned short u16x8;
typedef __attribute__((ext_vector_type(4))) unsigned short u16x4;
typedef __attribute__((ext_vector_type(4))) short s16x4;
typedef __attribute__((ext_vector_type(2))) unsigned u32x2;

__device__ __forceinline__ unsigned short f2bf(float f) {
  unsigned u = __builtin_bit_cast(unsigned, f);
  u += 0x7FFFu + ((u >> 16) & 1u);      // round-to-nearest-even
  return (unsigned short)(u >> 16);
}

__device__ __forceinline__ bf16x8 ldb8(const unsigned short* p) {
  return *reinterpret_cast<const bf16x8*>(p);
}

__device__ __forceinline__ bf16x8 cvt8v(const float4 a, const float4 b) {
  u16x8 r;
  r[0] = f2bf(a.x); r[1] = f2bf(a.y); r[2] = f2bf(a.z); r[3] = f2bf(a.w);
  r[4] = f2bf(b.x); r[5] = f2bf(b.y); r[6] = f2bf(b.z); r[7] = f2bf(b.w);
  return __builtin_bit_cast(bf16x8, r);
}

// pack 2 f32 -> 1 dword of 2 bf16 (lo=a, hi=b); no builtin on gfx950 -> asm
__device__ __forceinline__ unsigned cvtpk(float a, float b) {
  unsigned r;
  asm("v_cvt_pk_bf16_f32 %0, %1, %2" : "=v"(r) : "v"(a), "v"(b));
  return r;
}

// ---------------- kernel 1: weights fp32 -> bf16 ---------------------------
// Wq scale = log2(e)/sqrt(32): QK^T emits scores in the log2 domain.
__global__ __launch_bounds__(256) void wconv(
    const float* __restrict__ Wq, const float* __restrict__ Wk,
    const float* __restrict__ Wv, const float* __restrict__ Wo,
    unsigned short* __restrict__ Wb) {
  int i = blockIdx.x * 256 + threadIdx.x;            // 65536 total
  const float s = 0.2550348675762546f;               // log2(e)/sqrt(32)
  Wb[i]          = f2bf(Wq[i] * s);
  Wb[65536 + i]  = f2bf(Wk[i]);
  Wb[131072 + i] = f2bf(Wv[i]);
  Wb[196608 + i] = f2bf(Wo[i]);
}

// ---------------- kernel 2: Q/K/V projections (bf16 MFMA GEMM) -------------
// grid 768: m = bid>>8 (0=Q,1=K,2=V), 256 row-blocks of 32 rows.
__global__ __launch_bounds__(256) void qkv_proj(
    const float* __restrict__ X, const unsigned short* __restrict__ Wb,
    unsigned short* __restrict__ Qb, unsigned short* __restrict__ Kb,
    unsigned short* __restrict__ Vt) {
  int bid = blockIdx.x;
  int m = bid >> 8;
  int r0 = (bid & 255) * 32;
  int tid = threadIdx.x, lane = tid & 63, wave = tid >> 6;
  int wr = (wave >> 1) * 16, wc = (wave & 1) * 128;
  int lr = lane & 15, kgrp = (lane >> 4) * 8;
  const unsigned short* W = Wb + m * 65536;
  int arow = r0 + wr + lr;

  bf16x8 afrag[8];
#pragma unroll
  for (int k = 0; k < 8; ++k) {
    const float* p = &X[arow * 256 + k * 32 + kgrp];
    float4 a = *reinterpret_cast<const float4*>(p);
    float4 b = *reinterpret_cast<const float4*>(p + 4);
    afrag[k] = cvt8v(a, b);
  }

#pragma unroll
  for (int t = 0; t < 8; ++t) {
    int c0 = wc + t * 16;
    int wrow = c0 + lr;
    f32x4 acc = {0.f, 0.f, 0.f, 0.f};
#pragma unroll
    for (int k = 0; k < 8; ++k) {
      bf16x8 bfrag = ldb8(&W[wrow * 256 + k * 32 + kgrp]);
      acc = __builtin_amdgcn_mfma_f32_16x16x32_bf16(afrag[k], bfrag, acc, 0, 0, 0);
    }
    int col = c0 + lr;          // output column (C-layout: col = lane&15)
    int h = col >> 5, d = col & 31;
#pragma unroll
    for (int e = 0; e < 4; ++e) {
      int gr = r0 + wr + (lane >> 4) * 4 + e;   // C-layout row
      int b = gr >> 12, nq = gr & 4095;
      unsigned short v = f2bf(acc[e]);
      if (m == 0)      Qb[((b * 8 + h) * 4096 + nq) * 32 + d] = v;
      else if (m == 1) Kb[((b * 8 + h) * 4096 + nq) * 32 + d] = v;
      else             Vt[((b * 8 + h) * 32 + d) * 4096 + nq] = v;   // transposed
    }
  }
}

// ---------------- kernel 3: fused attention, in-register P (R4 skeleton) ---
// Swapped QK^T (S^T = mfma(K,Q), R4-verified): lane (lr,lg) owns q-row lr,
// k = 16kt+4lg+r lane-local. With the no-shift softmax (R10: |s| bounded)
// there is NO softmax section at all: P = adj * exp2(s) (scores arrive in the
// log2 domain, R11). P packs via cvt_pk straight into the B-frag of
// mfma_f32_16x16x16bf16_1k (R4-verified); PV accumulates O^T. Rowsum = in-
// lane adds + shfl_xor(16,32) (R4-verified), no rescale. NO LDS, no fences,
// no barriers. Adjacency = per-lane float4 rows (1KB/instr), u32 saddr+
// voffset addressing (R11), issued at iteration top (max distance from use).
// 256 thr = 4 waves = 4 heads; grid 2048 = (b,ks) x 128 qtiles x 2 hg.
__global__ __launch_bounds__(256, 3) void attn(
    const unsigned short* __restrict__ Qb, const unsigned short* __restrict__ Kb,
    const unsigned short* __restrict__ Vt, const float* __restrict__ Adj,
    float* __restrict__ Opart, float* __restrict__ Ml) {
  int rid = blockIdx.x;
  int cid = (rid & 7) * 256 + (rid >> 3);      // bijective (2048 = 8*256)
  int hg = cid & 1;
  int qb = (cid >> 1) & 127;
  int c  = cid >> 8;                           // 0..7 = b*4+ks
  int b = c >> 2, ks = c & 3;
  int q0 = qb * 32;
  int k_base = ks * 1024;

  int tid = threadIdx.x, lane = tid & 63, w = tid >> 6;
  int h = hg * 4 + w;
  int lr = lane & 15, lg = lane >> 4;
  int lg4 = lg * 4;

  const unsigned short* Qh = Qb + (size_t)(b * 8 + h) * 4096 * 32;
  const unsigned short* Kh = Kb + (size_t)(b * 8 + h) * 4096 * 32;
  const unsigned short* Vh = Vt + (size_t)(b * 8 + h) * 32 * 4096;
  const char* adjC = (const char*)(Adj + (size_t)b * 4096 * 4096);

  const f32x4 Z4 = {0.f, 0.f, 0.f, 0.f};

  bf16x8 qfrag[2];                   // B-operand of swapped QK^T
#pragma unroll
  for (int qt = 0; qt < 2; ++qt)
    qfrag[qt] = ldb8(&Qh[(q0 + qt * 16 + lr) * 32 + lg * 8]);

  // loop-invariant u32 BYTE offsets: this lane's adj row (q0+qt*16+lr),
  // column group lg4 (float4). (row*4096+col)*4 <= 67MB fits u32.
  unsigned aoff[2];
#pragma unroll
  for (int qt = 0; qt < 2; ++qt)
    aoff[qt] = (unsigned)((((q0 + qt * 16 + lr) << 12) + lg4) << 2);

  float lrow[2] = {0.f, 0.f};
  f32x4 oacc[2][2];                  // [qt][dt]: O^T tile, row=d, col=q=lr
  oacc[0][0] = Z4; oacc[0][1] = Z4; oacc[1][0] = Z4; oacc[1][1] = Z4;

  for (int kt0 = k_base; kt0 < k_base + 1024; kt0 += 64) {
    // ---- adjacency float4 loads at iteration top (consumed after QK^T+exp2)
    const char* adjI = adjC + ((unsigned)kt0 << 2);
    float4 ad[2][4];
#pragma unroll
    for (int qt = 0; qt < 2; ++qt)
#pragma unroll
      for (int kt = 0; kt < 4; ++kt)
        ad[qt][kt] = *reinterpret_cast<const float4*>(
            adjI + (aoff[qt] + (kt << 6)));

    // ---- S^T = K Q^T : 8 MFMA; lane holds S[q=lr][k=kt*16+lg4+reg]
    f32x4 sacc[2][4];
#pragma unroll
    for (int kt = 0; kt < 4; ++kt) {
      bf16x8 kf = ldb8(&Kh[(kt0 + kt * 16 + lr) * 32 + lg * 8]);
      sacc[0][kt] = __builtin_amdgcn_mfma_f32_16x16x32_bf16(kf, qfrag[0], Z4, 0, 0, 0);
      sacc[1][kt] = __builtin_amdgcn_mfma_f32_16x16x32_bf16(kf, qfrag[1], Z4, 0, 0, 0);
    }

    // ---- P = adj * exp2(s); pack -> B-frag; PV 16x16x16 into O^T
    f32x4 rsv[2] = {Z4, Z4};
#pragma unroll
    for (int kt = 0; kt < 4; ++kt) {
      s16x4 vf[2];                  // A-frag: V^T[d=dt*16+lr][k=kt*16+lg4+j]
#pragma unroll
      for (int dt = 0; dt < 2; ++dt)
        vf[dt] = *reinterpret_cast<const s16x4*>(
            &Vh[(dt * 16 + lr) * 4096 + kt0 + kt * 16 + lg4]);
#pragma unroll
      for (int qt = 0; qt < 2; ++qt) {
        float p0 = ad[qt][kt].x * __builtin_amdgcn_exp2f(sacc[qt][kt][0]);
        float p1 = ad[qt][kt].y * __builtin_amdgcn_exp2f(sacc[qt][kt][1]);
        float p2 = ad[qt][kt].z * __builtin_amdgcn_exp2f(sacc[qt][kt][2]);
        float p3 = ad[qt][kt].w * __builtin_amdgcn_exp2f(sacc[qt][kt][3]);
        rsv[qt][0] += p0; rsv[qt][1] += p1; rsv[qt][2] += p2; rsv[qt][3] += p3;
        unsigned w0 = cvtpk(p0, p1), w1 = cvtpk(p2, p3);
        s16x4 pb = __builtin_bit_cast(s16x4, (u32x2){w0, w1});
#pragma unroll
        for (int dt = 0; dt < 2; ++dt)
          oacc[qt][dt] = __builtin_amdgcn_mfma_f32_16x16x16bf16_1k(
              vf[dt], pb, oacc[qt][dt], 0, 0, 0);
      }
    }

    // ---- rowsum: in-lane horizontal + shfl_xor(16,32)  (no rescale)
#pragma unroll
    for (int qt = 0; qt < 2; ++qt) {
      float rs = (rsv[qt][0] + rsv[qt][1]) + (rsv[qt][2] + rsv[qt][3]);
      rs += __shfl_xor(rs, 16);
      rs += __shfl_xor(rs, 32);
      lrow[qt] += rs;
    }
  }

  // ---- epilogue: store raw partial O^T (as [q-row][d]) and per-row (m=0, l)
  float* Op = Opart + ((((size_t)ks * 2 + b) * 128 + qb) * 8 + h) * 1024;
#pragma unroll
  for (int qt = 0; qt < 2; ++qt)
#pragma unroll
    for (int dt = 0; dt < 2; ++dt)
      *reinterpret_cast<f32x4*>(&Op[(qt * 16 + lr) * 32 + dt * 16 + lg4]) =
          oacc[qt][dt];
  float* MlP = Ml + ((((size_t)ks * 2 + b) * 128 + qb) * 8 + h) * 64;
  if (lane < 16) {
#pragma unroll
    for (int qt = 0; qt < 2; ++qt) {
      float2 ml = {0.0f, lrow[qt]};        // m == 0 (no shift)
      *reinterpret_cast<float2*>(&MlP[(qt * 16 + lr) * 2]) = ml;
    }
  }
}

// ---------------- kernel 3b: combine k-split partials -> bf16 AO -----------
// grid 2048 (b x 128 qtiles x 8 heads), 256 threads: row = tid>>3, 4 cols each.
__global__ __launch_bounds__(256) void combine(
    const float* __restrict__ Opart, const float* __restrict__ Ml,
    unsigned short* __restrict__ AObf) {
  int bid = blockIdx.x;
  int b = bid >> 10, qb = (bid >> 3) & 127, h = bid & 7;
  int tid = threadIdx.x, row = tid >> 3, cg = (tid & 7) * 4;
  size_t base = (((size_t)b * 128 + qb) * 8 + h);
  const size_t ostr = 2097152, mstr = 131072;

  float m[4], l[4];
#pragma unroll
  for (int s = 0; s < 4; ++s) {
    const float* p = Ml + s * mstr + base * 64 + row * 2;
    m[s] = p[0]; l[s] = p[1];
  }
  float M = fmaxf(fmaxf(m[0], m[1]), fmaxf(m[2], m[3]));
  float e[4], L = 0.f;
#pragma unroll
  for (int s = 0; s < 4; ++s) { e[s] = __expf(m[s] - M); L += l[s] * e[s]; }
  float invL = 1.0f / L;

  float4 acc = {0.f, 0.f, 0.f, 0.f};
#pragma unroll
  for (int s = 0; s < 4; ++s) {
    float4 o = *reinterpret_cast<const float4*>(
        Opart + s * ostr + base * 1024 + row * 32 + cg);
    acc.x += o.x * e[s]; acc.y += o.y * e[s];
    acc.z += o.z * e[s]; acc.w += o.w * e[s];
  }
  u16x4 r4;
  r4[0] = f2bf(acc.x * invL); r4[1] = f2bf(acc.y * invL);
  r4[2] = f2bf(acc.z * invL); r4[3] = f2bf(acc.w * invL);
  size_t orow = ((size_t)b * 4096 + qb * 32 + row) * 256 + h * 32 + cg;
  *reinterpret_cast<u16x4*>(AObf + orow) = r4;
}

// ---------------- kernel 4: output projection + bias -----------------------
// grid 256 row-blocks of 32 rows. A input already bf16.
__global__ __launch_bounds__(256) void out_proj(
    const unsigned short* __restrict__ AObf, const unsigned short* __restrict__ Wob,
    const float* __restrict__ bo, float* __restrict__ Out) {
  int r0 = blockIdx.x * 32;
  int tid = threadIdx.x, lane = tid & 63, wave = tid >> 6;
  int wr = (wave >> 1) * 16, wc = (wave & 1) * 128;
  int lr = lane & 15, kgrp = (lane >> 4) * 8;
  int arow = r0 + wr + lr;

  bf16x8 afrag[8];
#pragma unroll
  for (int k = 0; k < 8; ++k)
    afrag[k] = ldb8(&AObf[arow * 256 + k * 32 + kgrp]);

#pragma unroll
  for (int t = 0; t < 8; ++t) {
    int c0 = wc + t * 16;
    int wrow = c0 + lr;
    f32x4 acc = {0.f, 0.f, 0.f, 0.f};
#pragma unroll
    for (int k = 0; k < 8; ++k) {
      bf16x8 bfrag = ldb8(&Wob[wrow * 256 + k * 32 + kgrp]);
      acc = __builtin_amdgcn_mfma_f32_16x16x32_bf16(afrag[k], bfrag, acc, 0, 0, 0);
    }
    float bias = bo[c0 + lr];
#pragma unroll
    for (int e = 0; e < 4; ++e) {
      int gr = r0 + wr + (lane >> 4) * 4 + e;
      Out[(size_t)gr * 256 + c0 + lr] = acc[e] + bias;
    }
  }
}

// ---------------------------------------------------------------------------
extern "C" void kernel_launch(void* const* d_in, const int* in_sizes, int n_in,
                              void* d_out, int out_size, void* d_ws, size_t ws_size,
                              hipStream_t stream) {
  const float* X   = (const float*)d_in[0];   // (2,4096,256)
  const float* Adj = (const float*)d_in[1];   // (2,4096,4096)
  const float* Wq  = (const float*)d_in[2];
  const float* Wk  = (const float*)d_in[3];
  const float* Wv  = (const float*)d_in[4];
  const float* Wo  = (const float*)d_in[5];
  const float* bo  = (const float*)d_in[6];
  float* Out = (float*)d_out;

  unsigned short* ws = (unsigned short*)d_ws;
  unsigned short* Wb   = ws;                      // 4 x 65536 bf16     (0.5 MB)
  unsigned short* Qb   = ws + 262144;             // (2,8,4096,32) bf16 (4 MB)
  unsigned short* Kb   = Qb + 2097152;            // (2,8,4096,32) bf16 (4 MB)
  unsigned short* Vt   = Kb + 2097152;            // (2,8,32,4096) bf16 (4 MB)
  unsigned short* AObf = Vt + 2097152;            // (2,4096,256) bf16  (4 MB)
  float* Opart = (float*)(AObf + 2097152);        // 4 splits x 2MB floats (33.5 MB)
  float* Ml    = Opart + 4 * 2097152;             // 4 x 131072 floats  (2.1 MB)

  hipLaunchKernelGGL(wconv,    dim3(256),  dim3(256), 0, stream, Wq, Wk, Wv, Wo, Wb);
  hipLaunchKernelGGL(qkv_proj, dim3(768),  dim3(256), 0, stream, X, Wb, Qb, Kb, Vt);
  hipLaunchKernelGGL(attn,     dim3(2048), dim3(256), 0, stream, Qb, Kb, Vt, Adj, Opart, Ml);
  hipLaunchKernelGGL(combine,  dim3(2048), dim3(256), 0, stream, Opart, Ml, AObf);
  hipLaunchKernelGGL(out_proj, dim3(256),  dim3(256), 0, stream, AObf, Wb + 196608, bo, Out);
}

// Round 14
// 177.038 us; speedup vs baseline: 1.7783x; 1.7783x over previous
//
#include <hip/hip_runtime.h>
#include <hip/hip_bf16.h>

typedef __attribute__((ext_vector_type(8))) __bf16 bf16x8;
typedef __attribute__((ext_vector_type(4))) float f32x4;
typedef __attribute__((ext_vector_type(8))) unsigned short u16x8;
typedef __attribute__((ext_vector_type(4))) unsigned short u16x4;

__device__ __forceinline__ unsigned short f2bf(float f) {
  unsigned u = __builtin_bit_cast(unsigned, f);
  u += 0x7FFFu + ((u >> 16) & 1u);      // round-to-nearest-even
  return (unsigned short)(u >> 16);
}

__device__ __forceinline__ bf16x8 ldb8(const unsigned short* p) {
  return *reinterpret_cast<const bf16x8*>(p);
}

__device__ __forceinline__ bf16x8 cvt8v(const float4 a, const float4 b) {
  u16x8 r;
  r[0] = f2bf(a.x); r[1] = f2bf(a.y); r[2] = f2bf(a.z); r[3] = f2bf(a.w);
  r[4] = f2bf(b.x); r[5] = f2bf(b.y); r[6] = f2bf(b.z); r[7] = f2bf(b.w);
  return __builtin_bit_cast(bf16x8, r);
}

// ---------------- kernel 1: weights fp32 -> bf16 ---------------------------
// Wq scale = log2(e)/sqrt(32): QK^T emits scores in the log2 domain, so the
// attention P-loop uses exp2(s) directly.
__global__ __launch_bounds__(256) void wconv(
    const float* __restrict__ Wq, const float* __restrict__ Wk,
    const float* __restrict__ Wv, const float* __restrict__ Wo,
    unsigned short* __restrict__ Wb) {
  int i = blockIdx.x * 256 + threadIdx.x;            // 65536 total
  const float s = 0.2550348675762546f;               // log2(e)/sqrt(32)
  Wb[i]          = f2bf(Wq[i] * s);
  Wb[65536 + i]  = f2bf(Wk[i]);
  Wb[131072 + i] = f2bf(Wv[i]);
  Wb[196608 + i] = f2bf(Wo[i]);
}

// ---------------- kernel 2: Q/K/V projections (bf16 MFMA GEMM) -------------
// grid 768: m = bid>>8 (0=Q,1=K,2=V), 256 row-blocks of 32 rows.
__global__ __launch_bounds__(256) void qkv_proj(
    const float* __restrict__ X, const unsigned short* __restrict__ Wb,
    unsigned short* __restrict__ Qb, unsigned short* __restrict__ Kb,
    unsigned short* __restrict__ Vt) {
  int bid = blockIdx.x;
  int m = bid >> 8;
  int r0 = (bid & 255) * 32;
  int tid = threadIdx.x, lane = tid & 63, wave = tid >> 6;
  int wr = (wave >> 1) * 16, wc = (wave & 1) * 128;
  int lr = lane & 15, kgrp = (lane >> 4) * 8;
  const unsigned short* W = Wb + m * 65536;
  int arow = r0 + wr + lr;

  bf16x8 afrag[8];
#pragma unroll
  for (int k = 0; k < 8; ++k) {
    const float* p = &X[arow * 256 + k * 32 + kgrp];
    float4 a = *reinterpret_cast<const float4*>(p);
    float4 b = *reinterpret_cast<const float4*>(p + 4);
    afrag[k] = cvt8v(a, b);
  }

#pragma unroll
  for (int t = 0; t < 8; ++t) {
    int c0 = wc + t * 16;
    int wrow = c0 + lr;
    f32x4 acc = {0.f, 0.f, 0.f, 0.f};
#pragma unroll
    for (int k = 0; k < 8; ++k) {
      bf16x8 bfrag = ldb8(&W[wrow * 256 + k * 32 + kgrp]);
      acc = __builtin_amdgcn_mfma_f32_16x16x32_bf16(afrag[k], bfrag, acc, 0, 0, 0);
    }
    int col = c0 + lr;          // output column (C-layout: col = lane&15)
    int h = col >> 5, d = col & 31;
#pragma unroll
    for (int e = 0; e < 4; ++e) {
      int gr = r0 + wr + (lane >> 4) * 4 + e;   // C-layout row
      int b = gr >> 12, nq = gr & 4095;
      unsigned short v = f2bf(acc[e]);
      if (m == 0)      Qb[((b * 8 + h) * 4096 + nq) * 32 + d] = v;
      else if (m == 1) Kb[((b * 8 + h) * 4096 + nq) * 32 + d] = v;
      else             Vt[((b * 8 + h) * 32 + d) * 4096 + nq] = v;   // transposed
    }
  }
}

// ---------------- kernel 3: fused multi-head attention (k-split) -----------
// R11 text (best passing, attn ~160us) with ONE scheduling fix: the 32
// adjacency gathers are moved to the iteration TOP and pinned there by
// __builtin_amdgcn_sched_barrier(0). Diagnosis across R4/R8/R11/R13: the
// compiler minimizes liveness (VGPR_Count 52-72) and batches the HBM-latency
// adjacency gathers into register-bounded groups, serializing ~900cy HBM
// latency several times per iteration (~9000cy/iter measured vs ~1400cy of
// compute chain). The barrier makes all 32 destinations simultaneously live
// -> forced wide issue -> ONE HBM latency, hidden under K-loads + 8 MFMA +
// exp2. No-shift softmax (R10), log2-domain scores (R11), MFMA-ones rowsum
// (R9), u32 saddr+voffset addressing (R11) all unchanged.
// grid 2048 = (b,ks) x 128 qtiles x 2 hg; chunked XCD swizzle.
__global__ __launch_bounds__(256, 3) void attn(
    const unsigned short* __restrict__ Qb, const unsigned short* __restrict__ Kb,
    const unsigned short* __restrict__ Vt, const float* __restrict__ Adj,
    float* __restrict__ Opart, float* __restrict__ Ml) {
  int rid = blockIdx.x;
  int cid = (rid & 7) * 256 + (rid >> 3);      // bijective (2048 = 8*256)
  int hg = cid & 1;
  int qb = (cid >> 1) & 127;
  int c  = cid >> 8;                           // 0..7 = b*4+ks
  int b = c >> 2, ks = c & 3;
  int q0 = qb * 32;
  int k_base = ks * 1024;

  int tid = threadIdx.x, lane = tid & 63, w = tid >> 6;
  int h = hg * 4 + w;
  int lr = lane & 15, lg = lane >> 4;

  __shared__ unsigned short plds[4][32][72];   // per-wave P buffer (18 KB)

  const unsigned short* Qh = Qb + (size_t)(b * 8 + h) * 4096 * 32;
  const unsigned short* Kh = Kb + (size_t)(b * 8 + h) * 4096 * 32;
  const unsigned short* Vh = Vt + (size_t)(b * 8 + h) * 32 * 4096;
  const char* adjC = (const char*)(Adj + (size_t)b * 4096 * 4096);

  const f32x4 Z4 = {0.f, 0.f, 0.f, 0.f};

  // all-ones bf16 B-fragment for the row-sum MFMA column
  u16x8 one_u;
#pragma unroll
  for (int e = 0; e < 8; ++e) one_u[e] = 0x3F80;
  const bf16x8 onesf = __builtin_bit_cast(bf16x8, one_u);

  bf16x8 qfrag[2];
#pragma unroll
  for (int qt = 0; qt < 2; ++qt)
    qfrag[qt] = ldb8(&Qh[(q0 + qt * 16 + lr) * 32 + lg * 8]);

  // loop-invariant u32 BYTE offsets for this lane's adjacency elements
  unsigned aoff[2][4];
#pragma unroll
  for (int qt = 0; qt < 2; ++qt)
#pragma unroll
    for (int r = 0; r < 4; ++r)
      aoff[qt][r] = (unsigned)((((q0 + qt * 16 + lg * 4 + r) << 12) + lr) << 2);

  f32x4 oacc[2][2], oaccS[2];
#pragma unroll
  for (int qt = 0; qt < 2; ++qt) {
    oacc[qt][0] = Z4; oacc[qt][1] = Z4; oaccS[qt] = Z4;
  }

  for (int kt0 = k_base; kt0 < k_base + 1024; kt0 += 64) {
    // ---- adjacency gathers FIRST; sched_barrier(0) pins them here so all
    //      32 destinations are live at once -> single wide HBM issue.
    const char* adjI = adjC + ((unsigned)kt0 << 2);
    float adjv[2][4][4];
#pragma unroll
    for (int qt = 0; qt < 2; ++qt)
#pragma unroll
      for (int kt = 0; kt < 4; ++kt)
#pragma unroll
        for (int r = 0; r < 4; ++r)
          adjv[qt][kt][r] = *reinterpret_cast<const float*>(
              adjI + (aoff[qt][r] + (kt << 6)));
    __builtin_amdgcn_sched_barrier(0);

    // ---- S = Q K^T  (K = head_dim = 32 -> one MFMA per 16x16 tile)
    f32x4 sacc[2][4];
#pragma unroll
    for (int kt = 0; kt < 4; ++kt) {
      bf16x8 kf = ldb8(&Kh[(kt0 + kt * 16 + lr) * 32 + lg * 8]);
#pragma unroll
      for (int qt = 0; qt < 2; ++qt)
        sacc[qt][kt] = __builtin_amdgcn_mfma_f32_16x16x32_bf16(qfrag[qt], kf, Z4, 0, 0, 0);
    }

    // ---- P = adj * exp2(s)  (s pre-scaled by log2e; no shift, R10 bound)
#pragma unroll
    for (int qt = 0; qt < 2; ++qt)
#pragma unroll
      for (int kt = 0; kt < 4; ++kt)
#pragma unroll
        for (int r = 0; r < 4; ++r) {
          int row = qt * 16 + lg * 4 + r;
          float e = __builtin_amdgcn_exp2f(sacc[qt][kt][r]);
          float p = adjv[qt][kt][r] * e;
          unsigned u = __builtin_bit_cast(unsigned, p) + 0x8000u;
          plds[w][row][kt * 16 + lr] = (unsigned short)(u >> 16);
        }

    // order P writes (ushort) before P reads (bf16x8) -- TBAA can't see the dep
    asm volatile("s_waitcnt lgkmcnt(0)" ::: "memory");

    // ---- O += P V ; rowsum column += P * ones  (same C layout, free pipe)
#pragma unroll
    for (int kc = 0; kc < 2; ++kc) {
      bf16x8 vf[2];
#pragma unroll
      for (int dt = 0; dt < 2; ++dt)
        vf[dt] = ldb8(&Vh[(dt * 16 + lr) * 4096 + kt0 + kc * 32 + lg * 8]);
      bf16x8 pf[2];
#pragma unroll
      for (int qt = 0; qt < 2; ++qt)
        pf[qt] = ldb8(&plds[w][qt * 16 + lr][kc * 32 + lg * 8]);
#pragma unroll
      for (int qt = 0; qt < 2; ++qt) {
#pragma unroll
        for (int dt = 0; dt < 2; ++dt)
          oacc[qt][dt] = __builtin_amdgcn_mfma_f32_16x16x32_bf16(pf[qt], vf[dt], oacc[qt][dt], 0, 0, 0);
        oaccS[qt] = __builtin_amdgcn_mfma_f32_16x16x32_bf16(pf[qt], onesf, oaccS[qt], 0, 0, 0);
      }
    }
  }

  // ---- epilogue: store raw partial O and per-row (m=0, l=rowsum column)
  float* Op = Opart + ((((size_t)ks * 2 + b) * 128 + qb) * 8 + h) * 1024;
#pragma unroll
  for (int qt = 0; qt < 2; ++qt)
#pragma unroll
    for (int r = 0; r < 4; ++r) {
      int row = qt * 16 + lg * 4 + r;
#pragma unroll
      for (int dt = 0; dt < 2; ++dt)
        Op[row * 32 + dt * 16 + lr] = oacc[qt][dt][r];
    }
  float* MlP = Ml + ((((size_t)ks * 2 + b) * 128 + qb) * 8 + h) * 64;
  if (lr == 0) {
#pragma unroll
    for (int qt = 0; qt < 2; ++qt)
#pragma unroll
      for (int r = 0; r < 4; ++r) {
        int row = qt * 16 + lg * 4 + r;
        MlP[row * 2]     = 0.0f;            // m == 0 (no shift)
        MlP[row * 2 + 1] = oaccS[qt][r];
      }
  }
}

// ---------------- kernel 3b: combine k-split partials -> bf16 AO -----------
// grid 2048 (b x 128 qtiles x 8 heads), 256 threads: row = tid>>3, 4 cols each.
__global__ __launch_bounds__(256) void combine(
    const float* __restrict__ Opart, const float* __restrict__ Ml,
    unsigned short* __restrict__ AObf) {
  int bid = blockIdx.x;
  int b = bid >> 10, qb = (bid >> 3) & 127, h = bid & 7;
  int tid = threadIdx.x, row = tid >> 3, cg = (tid & 7) * 4;
  size_t base = (((size_t)b * 128 + qb) * 8 + h);
  const size_t ostr = 2097152, mstr = 131072;

  float m[4], l[4];
#pragma unroll
  for (int s = 0; s < 4; ++s) {
    const float* p = Ml + s * mstr + base * 64 + row * 2;
    m[s] = p[0]; l[s] = p[1];
  }
  float M = fmaxf(fmaxf(m[0], m[1]), fmaxf(m[2], m[3]));
  float e[4], L = 0.f;
#pragma unroll
  for (int s = 0; s < 4; ++s) { e[s] = __expf(m[s] - M); L += l[s] * e[s]; }
  float invL = 1.0f / L;

  float4 acc = {0.f, 0.f, 0.f, 0.f};
#pragma unroll
  for (int s = 0; s < 4; ++s) {
    float4 o = *reinterpret_cast<const float4*>(
        Opart + s * ostr + base * 1024 + row * 32 + cg);
    acc.x += o.x * e[s]; acc.y += o.y * e[s];
    acc.z += o.z * e[s]; acc.w += o.w * e[s];
  }
  u16x4 r4;
  r4[0] = f2bf(acc.x * invL); r4[1] = f2bf(acc.y * invL);
  r4[2] = f2bf(acc.z * invL); r4[3] = f2bf(acc.w * invL);
  size_t orow = ((size_t)b * 4096 + qb * 32 + row) * 256 + h * 32 + cg;
  *reinterpret_cast<u16x4*>(AObf + orow) = r4;
}

// ---------------- kernel 4: output projection + bias -----------------------
// grid 256 row-blocks of 32 rows. A input already bf16.
__global__ __launch_bounds__(256) void out_proj(
    const unsigned short* __restrict__ AObf, const unsigned short* __restrict__ Wob,
    const float* __restrict__ bo, float* __restrict__ Out) {
  int r0 = blockIdx.x * 32;
  int tid = threadIdx.x, lane = tid & 63, wave = tid >> 6;
  int wr = (wave >> 1) * 16, wc = (wave & 1) * 128;
  int lr = lane & 15, kgrp = (lane >> 4) * 8;
  int arow = r0 + wr + lr;

  bf16x8 afrag[8];
#pragma unroll
  for (int k = 0; k < 8; ++k)
    afrag[k] = ldb8(&AObf[arow * 256 + k * 32 + kgrp]);

#pragma unroll
  for (int t = 0; t < 8; ++t) {
    int c0 = wc + t * 16;
    int wrow = c0 + lr;
    f32x4 acc = {0.f, 0.f, 0.f, 0.f};
#pragma unroll
    for (int k = 0; k < 8; ++k) {
      bf16x8 bfrag = ldb8(&Wob[wrow * 256 + k * 32 + kgrp]);
      acc = __builtin_amdgcn_mfma_f32_16x16x32_bf16(afrag[k], bfrag, acc, 0, 0, 0);
    }
    float bias = bo[c0 + lr];
#pragma unroll
    for (int e = 0; e < 4; ++e) {
      int gr = r0 + wr + (lane >> 4) * 4 + e;
      Out[(size_t)gr * 256 + c0 + lr] = acc[e] + bias;
    }
  }
}

// ---------------------------------------------------------------------------
extern "C" void kernel_launch(void* const* d_in, const int* in_sizes, int n_in,
                              void* d_out, int out_size, void* d_ws, size_t ws_size,
                              hipStream_t stream) {
  const float* X   = (const float*)d_in[0];   // (2,4096,256)
  const float* Adj = (const float*)d_in[1];   // (2,4096,4096)
  const float* Wq  = (const float*)d_in[2];
  const float* Wk  = (const float*)d_in[3];
  const float* Wv  = (const float*)d_in[4];
  const float* Wo  = (const float*)d_in[5];
  const float* bo  = (const float*)d_in[6];
  float* Out = (float*)d_out;

  unsigned short* ws = (unsigned short*)d_ws;
  unsigned short* Wb   = ws;                      // 4 x 65536 bf16     (0.5 MB)
  unsigned short* Qb   = ws + 262144;             // (2,8,4096,32) bf16 (4 MB)
  unsigned short* Kb   = Qb + 2097152;            // (2,8,4096,32) bf16 (4 MB)
  unsigned short* Vt   = Kb + 2097152;            // (2,8,32,4096) bf16 (4 MB)
  unsigned short* AObf = Vt + 2097152;            // (2,4096,256) bf16  (4 MB)
  float* Opart = (float*)(AObf + 2097152);        // 4 splits x 2MB floats (33.5 MB)
  float* Ml    = Opart + 4 * 2097152;             // 4 x 131072 floats  (2.1 MB)

  hipLaunchKernelGGL(wconv,    dim3(256),  dim3(256), 0, stream, Wq, Wk, Wv, Wo, Wb);
  hipLaunchKernelGGL(qkv_proj, dim3(768),  dim3(256), 0, stream, X, Wb, Qb, Kb, Vt);
  hipLaunchKernelGGL(attn,     dim3(2048), dim3(256), 0, stream, Qb, Kb, Vt, Adj, Opart, Ml);
  hipLaunchKernelGGL(combine,  dim3(2048), dim3(256), 0, stream, Opart, Ml, AObf);
  hipLaunchKernelGGL(out_proj, dim3(256),  dim3(256), 0, stream, AObf, Wb + 196608, bo, Out);
}